// Round 1
// baseline (11847.224 us; speedup 1.0000x reference)
//
#include <hip/hip_runtime.h>
#include <cstdint>
#include <cstddef>

typedef _Float16 half2_t __attribute__((ext_vector_type(2)));
typedef _Float16 half4_t __attribute__((ext_vector_type(4)));
typedef _Float16 half8_t __attribute__((ext_vector_type(8)));
typedef float    float4_t __attribute__((ext_vector_type(4)));

#define CAPLEN 65
#define NBLK 256   // persistent grid size (== #CUs)
#define HPAD 520   // LDS row stride in halfs for h staging (16B-aligned rows)

#if defined(__has_builtin)
#if __has_builtin(__builtin_amdgcn_fdot2)
#define HAS_FDOT2 1
#endif
#endif

__device__ __forceinline__ float fdot2f(half2_t a, half2_t b, float c) {
#ifdef HAS_FDOT2
  return __builtin_amdgcn_fdot2(a, b, c, false);
#else
  return c + (float)a[0]*(float)b[0] + (float)a[1]*(float)b[1];
#endif
}

__device__ __forceinline__ float fast_tanh(float x) {
  float e = __expf(2.f*x);
  return 1.f - 2.f/(e + 1.f);
}
__device__ __forceinline__ float fast_sig(float x) {
  return 1.f/(1.f + __expf(-x));
}

// ---------- fp32 -> fp16 convert (n % 4 == 0) ----------
__global__ void cvt_k(const float* __restrict__ s, _Float16* __restrict__ d, int n) {
  int i = (blockIdx.x*blockDim.x + threadIdx.x)*4;
  if (i < n) {
    float4 v = *(const float4*)(s + i);
    half4_t h;
    h[0] = (_Float16)v.x; h[1] = (_Float16)v.y; h[2] = (_Float16)v.z; h[3] = (_Float16)v.w;
    *(half4_t*)(d + i) = h;
  }
}

// bias sum + zero the grid-barrier state
__global__ void bias_sum_k(const float* __restrict__ a, const float* __restrict__ b,
                           float* __restrict__ o, unsigned* __restrict__ bar) {
  int i = blockIdx.x*blockDim.x + threadIdx.x;
  if (i < 2048) o[i] = a[i] + b[i];
  if (i < 2) bar[i] = 0u;
}

// gather embeddings for all (t,b): row r = t*32 + b, token = captions[b][t]
__global__ void gather_emb_k(const float* __restrict__ emb, const int* __restrict__ cap,
                             _Float16* __restrict__ X) {
  int r = blockIdx.x;
  int t = r >> 5, b = r & 31;
  int tok = cap[b*CAPLEN + t];
  const float* s = emb + (size_t)tok*512;
  _Float16* d = X + (size_t)r*512;
  for (int k = threadIdx.x; k < 512; k += blockDim.x) d[k] = (_Float16)s[k];
}

// feat_mean -> h0 (fp16), c0 (fp32); one wg per batch element
__global__ void init_state_k(const float* __restrict__ imgf,
                             const float* __restrict__ Wh0, const float* __restrict__ bh0,
                             const float* __restrict__ Wc0, const float* __restrict__ bc0,
                             float* __restrict__ c_state, _Float16* __restrict__ h0h) {
  __shared__ float fm[512];
  int b = blockIdx.x, tid = threadIdx.x;
  for (int dI = tid; dI < 512; dI += blockDim.x) {
    float s = 0.f;
    const float* p = imgf + ((size_t)b*196)*512 + dI;
    for (int n = 0; n < 196; n++) s += p[(size_t)n*512];
    fm[dI] = s * (1.f/196.f);
  }
  __syncthreads();
  for (int dI = tid; dI < 512; dI += blockDim.x) {
    const float* wh = Wh0 + (size_t)dI*512;
    const float* wc = Wc0 + (size_t)dI*512;
    float h = bh0[dI], c = bc0[dI];
    for (int k = 0; k < 512; k++) { h += fm[k]*wh[k]; c += fm[k]*wc[k]; }
    h0h[b*512 + dI] = (_Float16)h;
    c_state[b*512 + dI] = c;
  }
}

// Generic C = A * B^T (+bias), fp16 in, fp32 acc, MFMA 16x16x32.
// MODE 0: fp32 C (+bias). MODE 1: fp16 C.
template<int MODE>
__global__ void __launch_bounds__(256) gemm_abt_k(const _Float16* __restrict__ A, int lda,
    const _Float16* __restrict__ B, int ldb, void* __restrict__ Cp, int ldc,
    const float* __restrict__ bias, int K) {
  int wave = threadIdx.x >> 6, lane = threadIdx.x & 63;
  int m0 = blockIdx.y*128 + (wave >> 1)*64;
  int n0 = blockIdx.x*128 + (wave & 1)*64;
  int lr = lane & 15, quad = lane >> 4;
  float4_t acc[4][4];
  #pragma unroll
  for (int i = 0; i < 4; i++)
    #pragma unroll
    for (int j = 0; j < 4; j++)
      acc[i][j] = (float4_t){0.f, 0.f, 0.f, 0.f};
  const _Float16* Ap = A + (size_t)(m0 + lr)*lda + quad*8;
  const _Float16* Bp = B + (size_t)(n0 + lr)*ldb + quad*8;
  for (int k0 = 0; k0 < K; k0 += 32) {
    half8_t af[4], bf[4];
    #pragma unroll
    for (int i = 0; i < 4; i++) af[i] = *(const half8_t*)(Ap + (size_t)i*16*lda + k0);
    #pragma unroll
    for (int i = 0; i < 4; i++) bf[i] = *(const half8_t*)(Bp + (size_t)i*16*ldb + k0);
    #pragma unroll
    for (int mi = 0; mi < 4; mi++)
      #pragma unroll
      for (int ni = 0; ni < 4; ni++)
        acc[mi][ni] = __builtin_amdgcn_mfma_f32_16x16x32_f16(af[mi], bf[ni], acc[mi][ni], 0, 0, 0);
  }
  #pragma unroll
  for (int mi = 0; mi < 4; mi++) {
    #pragma unroll
    for (int ni = 0; ni < 4; ni++) {
      int col = n0 + ni*16 + lr;
      float bv = (MODE == 1) ? 0.f : bias[col];
      #pragma unroll
      for (int r = 0; r < 4; r++) {
        int row = m0 + mi*16 + quad*4 + r;
        if (MODE == 1) {
          ((_Float16*)Cp)[(size_t)row*ldc + col] = (_Float16)acc[mi][ni][r];
        } else {
          ((float*)Cp)[(size_t)row*ldc + col] = acc[mi][ni][r] + bv;
        }
      }
    }
  }
}

// ---- custom device-wide barrier (sense-reversing; agent-scope atomics) ----
// Safe: grid = 256 blocks == #CUs; __launch_bounds__(256,2) guarantees >=2
// resident blocks/CU of capacity, so all 256 blocks are co-resident.
__device__ __forceinline__ void grid_barrier(unsigned* __restrict__ bar) {
  __syncthreads();
  __threadfence();                      // release my writes (agent scope)
  if (threadIdx.x == 0) {
    unsigned g = __hip_atomic_load(bar + 1, __ATOMIC_RELAXED, __HIP_MEMORY_SCOPE_AGENT);
    unsigned a = __hip_atomic_fetch_add(bar + 0, 1u, __ATOMIC_ACQ_REL, __HIP_MEMORY_SCOPE_AGENT) + 1u;
    if (a == (unsigned)NBLK) {
      __hip_atomic_store(bar + 0, 0u, __ATOMIC_RELAXED, __HIP_MEMORY_SCOPE_AGENT);
      __hip_atomic_store(bar + 1, g + 1u, __ATOMIC_RELEASE, __HIP_MEMORY_SCOPE_AGENT);
    } else {
      while (__hip_atomic_load(bar + 1, __ATOMIC_RELAXED, __HIP_MEMORY_SCOPE_AGENT) == g)
        __builtin_amdgcn_s_sleep(2);
    }
  }
  __syncthreads();
  __threadfence();                      // acquire side: invalidate stale caches
}

// ---- persistent kernel: all 64 LSTM+attention steps in one launch ----
// 256 blocks x 256 threads. Per step:
//   P1 : hW = h@Wdec^T (d-distributed), Gpart = Xg[t] + h@Whh^T (row-distributed)
//   bar
//   P23: block (b = bid&31 [XCD-aligned], rchunk = bid>>5):
//        e = v.tanh(fproj[b]+hW[b]) ; softmax ; gates = Gpart + alpha @ P[b]
//        pointwise LSTM (c in registers) ; write h, H
//   bar
__global__ void __launch_bounds__(256, 2) loop_k(
    const _Float16* __restrict__ Wdec_h,   // [512][512]
    const _Float16* __restrict__ Whh_h,    // [2048][512]
    const _Float16* __restrict__ fproj_h,  // [32][196][512]
    const _Float16* __restrict__ P_h,      // [32][196][2048]
    const float*    __restrict__ Xg,       // [64*32][2048] (incl. biases)
    const float*    __restrict__ v_att,    // [512]
    const float*    __restrict__ c_init,   // [32][512]
    _Float16*       __restrict__ hbuf,     // [32][512] (preloaded h0)
    float*          __restrict__ hw_g,     // [32][512]
    float*          __restrict__ gpart_g,  // [32][2048]
    _Float16*       __restrict__ H_h,      // [64*32][512]
    float*          __restrict__ out_alpha,// [32][64][196]
    unsigned*       __restrict__ bar) {
  __shared__ _Float16 h_lds[32*HPAD];
  __shared__ float vl[512];
  __shared__ float hwl[512];
  __shared__ float sm_r[256];
  __shared__ float sm_a[256];
  __shared__ float sm_g[256];
  int bid = blockIdx.x, tid = threadIdx.x;
  int b = bid & 31, rchunk = bid >> 5;

  for (int i = tid; i < 512; i += 256) vl[i] = v_att[i];
  float c_reg = 0.f;
  if (tid < 64) c_reg = c_init[b*512 + (rchunk << 6) + tid];

  for (int t = 0; t < 64; ++t) {
    // ---------------- P1 ----------------
    // stage h (32x512 fp16) into LDS, padded rows
    for (int i = tid; i < 2048; i += 256) {
      int bb = i >> 6, k8 = i & 63;
      *(half8_t*)(h_lds + bb*HPAD + k8*8) = *(const half8_t*)(hbuf + bb*512 + k8*8);
    }
    __syncthreads();
    // Gpart rows [bid*8, bid*8+8): thread = (row_local, b)
    {
      int rl = tid >> 5, bb = tid & 31;
      int row = bid*8 + rl;
      const half8_t* w8p = (const half8_t*)(Whh_h + (size_t)row*512);
      const half8_t* h8p = (const half8_t*)(h_lds + bb*HPAD);
      float a0 = Xg[((size_t)t*32 + bb)*2048 + row], a1 = 0.f;
      for (int k8 = 0; k8 < 64; ++k8) {
        half8_t w8 = w8p[k8];
        half8_t h8 = h8p[k8];
        const half2_t* wp = (const half2_t*)&w8;
        const half2_t* hp = (const half2_t*)&h8;
        a0 = fdot2f(wp[0], hp[0], a0);
        a1 = fdot2f(wp[1], hp[1], a1);
        a0 = fdot2f(wp[2], hp[2], a0);
        a1 = fdot2f(wp[3], hp[3], a1);
      }
      gpart_g[bb*2048 + row] = a0 + a1;
    }
    // hW dims [bid*2, bid*2+2): threads 0..63
    if (tid < 64) {
      int dloc = tid >> 5, bb = tid & 31;
      int d = bid*2 + dloc;
      const half8_t* w8p = (const half8_t*)(Wdec_h + (size_t)d*512);
      const half8_t* h8p = (const half8_t*)(h_lds + bb*HPAD);
      float a0 = 0.f, a1 = 0.f;
      for (int k8 = 0; k8 < 64; ++k8) {
        half8_t w8 = w8p[k8];
        half8_t h8 = h8p[k8];
        const half2_t* wp = (const half2_t*)&w8;
        const half2_t* hp = (const half2_t*)&h8;
        a0 = fdot2f(wp[0], hp[0], a0);
        a1 = fdot2f(wp[1], hp[1], a1);
        a0 = fdot2f(wp[2], hp[2], a0);
        a1 = fdot2f(wp[3], hp[3], a1);
      }
      hw_g[bb*512 + d] = a0 + a1;
    }
    grid_barrier(bar);

    // ---------------- P23 ----------------
    for (int i = tid; i < 512; i += 256) hwl[i] = hw_g[b*512 + i];
    __syncthreads();
    // e[n] = sum_d v[d] * tanh(fproj[b][n][d] + hW[b][d])
    float e = -1e30f;
    if (tid < 196) {
      const half8_t* f8p = (const half8_t*)(fproj_h + ((size_t)b*196 + tid)*512);
      float a0 = 0.f, a1 = 0.f;
      for (int k8 = 0; k8 < 64; ++k8) {
        half8_t f = f8p[k8];
        #pragma unroll
        for (int j = 0; j < 8; j += 2) {
          int k = k8*8 + j;
          a0 += vl[k]   * fast_tanh((float)f[j]   + hwl[k]);
          a1 += vl[k+1] * fast_tanh((float)f[j+1] + hwl[k+1]);
        }
      }
      e = a0 + a1;
    }
    // softmax over 196 (block-local, 256-wide trees)
    sm_r[tid] = e;
    __syncthreads();
    for (int s = 128; s > 0; s >>= 1) {
      if (tid < s) sm_r[tid] = fmaxf(sm_r[tid], sm_r[tid+s]);
      __syncthreads();
    }
    float mx = sm_r[0];
    __syncthreads();
    float ex = (tid < 196) ? __expf(e - mx) : 0.f;
    sm_r[tid] = ex;
    __syncthreads();
    for (int s = 128; s > 0; s >>= 1) {
      if (tid < s) sm_r[tid] += sm_r[tid+s];
      __syncthreads();
    }
    float inv = 1.f / sm_r[0];
    float al = ex * inv;
    sm_a[tid] = al;
    if (tid < 196 && rchunk == 0)
      out_alpha[((size_t)b*64 + t)*196 + tid] = al;
    __syncthreads();
    // gates: rows {typ*512 + rchunk*64 + dl}; K = 196 over precomputed P
    {
      int typ = tid >> 6, dl = tid & 63;
      int row = (typ << 9) + (rchunk << 6) + dl;
      const _Float16* Pp = P_h + ((size_t)b*196)*2048 + row;
      float a0 = gpart_g[b*2048 + row], a1 = 0.f, a2 = 0.f, a3 = 0.f;
      for (int n = 0; n < 196; n += 4) {
        a0 += sm_a[n+0] * (float)Pp[(size_t)(n+0)*2048];
        a1 += sm_a[n+1] * (float)Pp[(size_t)(n+1)*2048];
        a2 += sm_a[n+2] * (float)Pp[(size_t)(n+2)*2048];
        a3 += sm_a[n+3] * (float)Pp[(size_t)(n+3)*2048];
      }
      sm_g[tid] = (a0 + a1) + (a2 + a3);
    }
    __syncthreads();
    if (tid < 64) {
      float ig = sm_g[tid], fg = sm_g[64+tid], gg = sm_g[128+tid], og = sm_g[192+tid];
      float cn = fast_sig(fg)*c_reg + fast_sig(ig)*fast_tanh(gg);
      float hn = fast_sig(og)*fast_tanh(cn);
      c_reg = cn;
      _Float16 hh = (_Float16)hn;
      hbuf[b*512 + (rchunk << 6) + tid] = hh;
      H_h[((size_t)t*32 + b)*512 + (rchunk << 6) + tid] = hh;
    }
    grid_barrier(bar);
  }
}

// ---- logits: out[b][t][:] = H[t*32+b] @ Wfc^T + bfc ----
// Persistent-N: each block owns a 128-col stripe of Wfc (read from HBM once,
// stays L2-hot) and loops over all 32 m-tiles. Nontemporal C stores.
__global__ void __launch_bounds__(512) logits_k(const _Float16* __restrict__ A,
    const _Float16* __restrict__ Bw, float* __restrict__ C,
    const float* __restrict__ bias) {
  int wave = threadIdx.x >> 6, lane = threadIdx.x & 63;
  int lr = lane & 15, quad = lane >> 4;
  int waveM = wave >> 1, waveN = wave & 1;
  int n0 = blockIdx.x*128 + waveN*64;
  const _Float16* Bp = Bw + (size_t)(n0 + lr)*512 + quad*8;
  float bv[4];
  #pragma unroll
  for (int ni = 0; ni < 4; ni++) bv[ni] = bias[n0 + ni*16 + lr];
  for (int it = 0; it < 8; ++it) {
    int m0 = (it*4 + waveM)*64;
    const _Float16* Ap = A + (size_t)(m0 + lr)*512 + quad*8;
    float4_t acc[4][4];
    #pragma unroll
    for (int i = 0; i < 4; i++)
      #pragma unroll
      for (int j = 0; j < 4; j++)
        acc[i][j] = (float4_t){0.f, 0.f, 0.f, 0.f};
    for (int k0 = 0; k0 < 512; k0 += 32) {
      half8_t af[4], bf[4];
      #pragma unroll
      for (int i = 0; i < 4; i++) af[i] = *(const half8_t*)(Ap + (size_t)i*16*512 + k0);
      #pragma unroll
      for (int i = 0; i < 4; i++) bf[i] = *(const half8_t*)(Bp + (size_t)i*16*512 + k0);
      #pragma unroll
      for (int mi = 0; mi < 4; mi++)
        #pragma unroll
        for (int ni = 0; ni < 4; ni++)
          acc[mi][ni] = __builtin_amdgcn_mfma_f32_16x16x32_f16(af[mi], bf[ni], acc[mi][ni], 0, 0, 0);
    }
    #pragma unroll
    for (int mi = 0; mi < 4; mi++) {
      #pragma unroll
      for (int ni = 0; ni < 4; ni++) {
        int col = n0 + ni*16 + lr;
        #pragma unroll
        for (int r = 0; r < 4; r++) {
          int row = m0 + mi*16 + quad*4 + r;
          size_t orow = (size_t)((row & 31)*64 + (row >> 5));   // -> out[b][t]
          __builtin_nontemporal_store(acc[mi][ni][r] + bv[ni], C + orow*32000 + col);
        }
      }
    }
  }
}

extern "C" void kernel_launch(void* const* d_in, const int* in_sizes, int n_in,
                              void* d_out, int out_size, void* d_ws, size_t ws_size,
                              hipStream_t stream) {
  const float* imgf  = (const float*)d_in[0];
  const int*   cap   = (const int*)d_in[1];
  const float* emb   = (const float*)d_in[2];
  const float* Wh0   = (const float*)d_in[3];
  const float* bh0   = (const float*)d_in[4];
  const float* Wc0   = (const float*)d_in[5];
  const float* bc0   = (const float*)d_in[6];
  const float* Wenc  = (const float*)d_in[7];
  const float* Wdec  = (const float*)d_in[8];
  const float* v_att = (const float*)d_in[9];
  const float* W_ih  = (const float*)d_in[10];
  const float* b_ih  = (const float*)d_in[11];
  const float* W_hh  = (const float*)d_in[12];
  const float* b_hh  = (const float*)d_in[13];
  const float* Wfc   = (const float*)d_in[14];
  const float* bfc   = (const float*)d_in[15];
  float* out = (float*)d_out;
  (void)in_sizes; (void)n_in; (void)out_size; (void)ws_size;

  char* ws = (char*)d_ws;
  size_t off = 0;
  auto alloc = [&](size_t bytes) -> void* {
    void* p = ws + off;
    off += (bytes + 255) & ~(size_t)255;
    return p;
  };
  _Float16* Wenc_h  = (_Float16*)alloc((size_t)512*512*2);
  _Float16* Wdec_h  = (_Float16*)alloc((size_t)512*512*2);
  _Float16* Wih_h   = (_Float16*)alloc((size_t)2048*1024*2);
  _Float16* Whh_h   = (_Float16*)alloc((size_t)2048*512*2);
  _Float16* Wfc_h   = (_Float16*)alloc((size_t)32000*512*2);
  _Float16* imgf_h  = (_Float16*)alloc((size_t)32*196*512*2);
  _Float16* fproj_h = (_Float16*)alloc((size_t)32*196*512*2);
  _Float16* P_h     = (_Float16*)alloc((size_t)32*196*2048*2);
  _Float16* X_h     = (_Float16*)alloc((size_t)64*32*512*2);
  float*    Xg      = (float*)alloc((size_t)64*32*2048*4);
  float*    bsum    = (float*)alloc((size_t)2048*4);
  float*    c_state = (float*)alloc((size_t)32*512*4);
  _Float16* hbuf    = (_Float16*)alloc((size_t)32*512*2);
  float*    hw_g    = (float*)alloc((size_t)32*512*4);
  float*    gpart_g = (float*)alloc((size_t)32*2048*4);
  _Float16* H_h     = (_Float16*)alloc((size_t)2048*512*2);
  unsigned* bar     = (unsigned*)alloc((size_t)256);

  auto cvt = [&](const float* s, _Float16* d, int n) {
    cvt_k<<<dim3((n/4 + 255)/256), dim3(256), 0, stream>>>(s, d, n);
  };
  cvt(Wenc, Wenc_h, 512*512);
  cvt(Wdec, Wdec_h, 512*512);
  cvt(W_ih, Wih_h, 2048*1024);
  cvt(W_hh, Whh_h, 2048*512);
  cvt(Wfc,  Wfc_h, 32000*512);
  cvt(imgf, imgf_h, 32*196*512);
  bias_sum_k<<<dim3(8), dim3(256), 0, stream>>>(b_ih, b_hh, bsum, bar);
  gather_emb_k<<<dim3(2048), dim3(256), 0, stream>>>(emb, cap, X_h);
  init_state_k<<<dim3(32), dim3(256), 0, stream>>>(imgf, Wh0, bh0, Wc0, bc0, c_state, hbuf);
  // feat_proj = image_features @ Wenc^T  -> fp16 [32*196, 512]
  gemm_abt_k<1><<<dim3(4, 49), dim3(256), 0, stream>>>(imgf_h, 512, Wenc_h, 512, fproj_h, 512, nullptr, 512);
  // P = image_features @ W_ih[:,512:]^T -> fp16 [32*196, 2048]  (ctx folded out)
  gemm_abt_k<1><<<dim3(16, 49), dim3(256), 0, stream>>>(imgf_h, 512, Wih_h + 512, 1024, P_h, 2048, nullptr, 512);
  // Xg = emb_x @ W_ih[:, :512]^T + (b_ih + b_hh)  -> fp32 [2048, 2048]
  gemm_abt_k<0><<<dim3(16, 16), dim3(256), 0, stream>>>(X_h, 512, Wih_h, 1024, Xg, 2048, bsum, 512);

  float* out_alpha = out + (size_t)32*64*32000;
  // all 64 recurrence steps in one persistent launch
  loop_k<<<dim3(NBLK), dim3(256), 0, stream>>>(Wdec_h, Whh_h, fproj_h, P_h, Xg,
      v_att, c_state, hbuf, hw_g, gpart_g, H_h, out_alpha, bar);
  // outputs = H @ Wfc^T + bfc (remapped rows)
  logits_k<<<dim3(250), dim3(512), 0, stream>>>(H_h, Wfc_h, out, bfc);
}